// Round 2
// baseline (5623.859 us; speedup 1.0000x reference)
//
#include <hip/hip_runtime.h>

// Problem constants: T=128, B=64, D=1024, H=1024
#define TT 128
#define BB 64
#define DD 1024
#define HH 1024
#define G4 4096          // 4*H
#define MM (TT*BB)       // 8192 rows of X flattened
#define BH (BB*HH)       // 65536, one timestep of h/out

__device__ __forceinline__ float hsig(float x) {
    x += 0.5f;
    return fminf(fmaxf(x, 0.0f), 1.0f);
}
__device__ __forceinline__ float htanh(float x) {
    return fminf(fmaxf(x, -1.0f), 1.0f);
}

// ---------------------------------------------------------------------------
// Pre-transpose Wh[k][g*1024+hc] -> Whp[k][hc][g] (float4 per (k,hc)).
// One element per thread; reads coalesced per gate, writes coalesced float4.
__global__ __launch_bounds__(256) void transpose_wh(const float* __restrict__ Wh,
                                                    float4* __restrict__ Whp) {
    int idx = blockIdx.x * 256 + threadIdx.x;   // 0 .. 1024*1024-1
    int k = idx >> 10;
    int hc = idx & 1023;
    const float* src = Wh + (size_t)k * G4 + hc;
    float4 v;
    v.x = src[0];
    v.y = src[1024];
    v.z = src[2048];
    v.w = src[3072];
    Whp[idx] = v;
}

// ---------------------------------------------------------------------------
// Gx[8192][4096] = X[8192][1024] @ Wx[1024][4096] + bias
// 128x128 tile, BK=16, 256 threads, 8x8 per thread (fragments split as
// {t*4..t*4+3} u {64+t*4..} so LDS b128 reads stay 2-way / conflict-free).
__global__ __launch_bounds__(256) void gx_gemm(const float* __restrict__ X,
                                               const float* __restrict__ W,
                                               const float* __restrict__ bias,
                                               float* __restrict__ C) {
    __shared__ float As[16][132];   // [k][m], row stride 132 (16B-aligned, pad)
    __shared__ float Bs[16][132];   // [k][n]

    const int tid = threadIdx.x;
    const int tx = tid & 15;        // n-quad selector
    const int ty = tid >> 4;        // m-quad selector
    const int m0 = blockIdx.y * 128;
    const int n0 = blockIdx.x * 128;

    float acc[8][8] = {};

    for (int k0 = 0; k0 < DD; k0 += 16) {
        // A tile: 128 m x 16 k, 512 float4 loads (transposed into LDS)
        #pragma unroll
        for (int i = 0; i < 2; ++i) {
            int f4 = tid + i * 256;
            int mi = f4 >> 2;            // 0..127
            int kq = f4 & 3;             // 0..3
            float4 v = *(const float4*)(X + (size_t)(m0 + mi) * DD + k0 + kq * 4);
            As[kq * 4 + 0][mi] = v.x;
            As[kq * 4 + 1][mi] = v.y;
            As[kq * 4 + 2][mi] = v.z;
            As[kq * 4 + 3][mi] = v.w;
        }
        // B tile: 16 k x 128 n, 512 float4 loads (direct)
        #pragma unroll
        for (int i = 0; i < 2; ++i) {
            int f4 = tid + i * 256;
            int r = f4 >> 5;             // 0..15
            int c = f4 & 31;             // 0..31
            float4 v = *(const float4*)(W + (size_t)(k0 + r) * G4 + n0 + c * 4);
            *(float4*)&Bs[r][c * 4] = v;
        }
        __syncthreads();

        #pragma unroll
        for (int kk = 0; kk < 16; ++kk) {
            float ar[8], br[8];
            *(float4*)&ar[0] = *(const float4*)&As[kk][ty * 4];
            *(float4*)&ar[4] = *(const float4*)&As[kk][64 + ty * 4];
            *(float4*)&br[0] = *(const float4*)&Bs[kk][tx * 4];
            *(float4*)&br[4] = *(const float4*)&Bs[kk][64 + tx * 4];
            #pragma unroll
            for (int i = 0; i < 8; ++i)
                #pragma unroll
                for (int j = 0; j < 8; ++j)
                    acc[i][j] += ar[i] * br[j];
        }
        __syncthreads();
    }

    // Epilogue: acc[i][j] -> row m0 + (i&3) + ty*4 + 64*(i>>2),
    //                        col n0 + (j&3) + tx*4 + 64*(j>>2)
    float bl[8];
    *(float4*)&bl[0] = *(const float4*)(bias + n0 + tx * 4);
    *(float4*)&bl[4] = *(const float4*)(bias + n0 + 64 + tx * 4);
    #pragma unroll
    for (int i = 0; i < 8; ++i) {
        int mrow = m0 + ty * 4 + (i & 3) + 64 * (i >> 2);
        float* crow = C + (size_t)mrow * G4 + n0;
        float4 o1, o2;
        o1.x = acc[i][0] + bl[0]; o1.y = acc[i][1] + bl[1];
        o1.z = acc[i][2] + bl[2]; o1.w = acc[i][3] + bl[3];
        o2.x = acc[i][4] + bl[4]; o2.y = acc[i][5] + bl[5];
        o2.z = acc[i][6] + bl[6]; o2.w = acc[i][7] + bl[7];
        *(float4*)(crow + tx * 4) = o1;
        *(float4*)(crow + 64 + tx * 4) = o2;
    }
}

// ---------------------------------------------------------------------------
// Fused recurrent step: gates = Gx[t] + h(t-1) @ Wh; hard-LSTM cell; write
// c (global scratch) and h (directly into out[t]). One launch per timestep.
// Grid: 256 wgs = 4 bgroups(16 b) x 64 hcspans(16 hc). Block: 512 thr =
// 16 hc x 16 b x 2 k-halves. Thread (b,hc) owns all 4 gates -> cell is
// thread-local; only cross-thread op is the 2-way k-half LDS reduce.
// wgid = bgroup*64 + hcspan => the 4 b-sharing wgs have the same wgid%8
// (same XCD), keeping each XCD's Whp slice footprint at 2 MB (L2-resident).
__global__ __launch_bounds__(512) void lstm_step(const float* __restrict__ Gxt,
                                                 const float4* __restrict__ Whp,
                                                 const float* __restrict__ hprev,
                                                 float* __restrict__ cbuf,
                                                 float* __restrict__ hout,
                                                 int t) {
    __shared__ float4 red[256];

    const int tid = threadIdx.x;
    const int hc_l = tid & 15;
    const int b_l  = (tid >> 4) & 15;
    const int kh   = tid >> 8;            // 0 or 1 (k-half)
    const int w = blockIdx.x;
    const int bgroup = w >> 6;            // 0..3
    const int hcspan = w & 63;            // 0..63
    const int b  = bgroup * 16 + b_l;
    const int hc = hcspan * 16 + hc_l;

    float4 acc = {0.0f, 0.0f, 0.0f, 0.0f};

    if (t > 0) {
        // h values: wave-subuniform (16 lanes share each address).
        const float4* hv4 = (const float4*)(hprev + (size_t)b * HH + kh * 512);
        // weight: one coalesced float4 per (k, lane): all 4 gates at once
        const float4* wp = Whp + (size_t)(kh * 512) * 1024 + hc;
        #pragma unroll 2
        for (int k4 = 0; k4 < 128; ++k4) {
            float4 hv = hv4[k4];
            float4 w0 = wp[0];
            float4 w1 = wp[1024];
            float4 w2 = wp[2048];
            float4 w3 = wp[3072];
            wp += 4096;
            acc.x += hv.x * w0.x; acc.y += hv.x * w0.y;
            acc.z += hv.x * w0.z; acc.w += hv.x * w0.w;
            acc.x += hv.y * w1.x; acc.y += hv.y * w1.y;
            acc.z += hv.y * w1.z; acc.w += hv.y * w1.w;
            acc.x += hv.z * w2.x; acc.y += hv.z * w2.y;
            acc.z += hv.z * w2.z; acc.w += hv.z * w2.w;
            acc.x += hv.w * w3.x; acc.y += hv.w * w3.y;
            acc.z += hv.w * w3.z; acc.w += hv.w * w3.w;
        }
    }

    if (kh == 1) red[tid & 255] = acc;
    __syncthreads();

    if (kh == 0) {
        float4 r = red[tid];
        const size_t gbase = (size_t)b * G4 + hc;
        float gi = acc.x + r.x + Gxt[gbase];
        float gf = acc.y + r.y + Gxt[gbase + 1024];
        float gg = acc.z + r.z + Gxt[gbase + 2048];
        float go = acc.w + r.w + Gxt[gbase + 3072];

        float ii = hsig(gi);
        float ff = hsig(gf);
        float gv = htanh(gg);
        float oo = hsig(go);

        const int cidx = b * HH + hc;
        float cv = (t > 0) ? cbuf[cidx] : 0.0f;
        float cn = ff * cv + ii * gv;
        cbuf[cidx] = cn;
        float hn = oo * htanh(cn);
        hout[cidx] = hn;
    }
}

// ---------------------------------------------------------------------------
extern "C" void kernel_launch(void* const* d_in, const int* in_sizes, int n_in,
                              void* d_out, int out_size, void* d_ws, size_t ws_size,
                              hipStream_t stream) {
    const float* x  = (const float*)d_in[0];   // [T,B,D]
    const float* Wx = (const float*)d_in[1];   // [D,4H]
    const float* Wh = (const float*)d_in[2];   // [H,4H]
    const float* bs = (const float*)d_in[3];   // [4H]
    float* out = (float*)d_out;                // [T,B,H] — doubles as h history

    // Workspace layout (floats): Gx 33,554,432 | Whp 4,194,304 | cbuf 65,536
    float*  Gx   = (float*)d_ws;
    float4* Whp  = (float4*)(Gx + (size_t)MM * G4);
    float*  cbuf = (float*)(Whp + (size_t)HH * HH);  // Whp is HH*HH float4s

    // Wh -> gate-packed layout (independent of gx_gemm; runs every call)
    transpose_wh<<<dim3(1024 * 1024 / 256), dim3(256), 0, stream>>>(Wh, Whp);

    // Gx = X @ Wx + b for all timesteps at once
    gx_gemm<<<dim3(G4 / 128, MM / 128), dim3(256), 0, stream>>>(x, Wx, bs, Gx);

    // Sequential recurrence; h history lives in `out` (step t reads out[t-1])
    for (int t = 0; t < TT; ++t) {
        const float* hprev = (t > 0) ? (out + (size_t)(t - 1) * BH) : out;
        lstm_step<<<dim3(256), dim3(512), 0, stream>>>(
            Gx + (size_t)t * BB * G4, Whp, hprev, cbuf, out + (size_t)t * BH, t);
    }
}

// Round 3
// 3756.804 us; speedup vs baseline: 1.4970x; 1.4970x over previous
//
#include <hip/hip_runtime.h>

// Problem constants: T=128, B=64, D=1024, H=1024. fp32 throughout (the
// recurrence is chaotic: bf16 gate noise would amplify ~50x past the 0.02
// threshold; fp32 order-noise lands at ~4e-3 absmax).
#define TT 128
#define BB 64
#define DD 1024
#define HH 1024
#define G4 4096          // 4*H
#define MM (TT*BB)       // 8192 rows of X flattened
#define BH (BB*HH)       // 65536, one timestep of h/out

__device__ __forceinline__ float hsig(float x) {
    x += 0.5f;
    return fminf(fmaxf(x, 0.0f), 1.0f);
}
__device__ __forceinline__ float htanh(float x) {
    return fminf(fmaxf(x, -1.0f), 1.0f);
}

// ---------------------------------------------------------------------------
// Gx[8192][4096] = X[8192][1024] @ Wx[1024][4096] + bias
// 128x128 tile, BK=16, 256 threads, 8x8/thread, global->register prefetch
// double-buffering (next tile's loads issue right after syncthreads and
// complete under the 1024-FMA compute phase).
__global__ __launch_bounds__(256) void gx_gemm(const float* __restrict__ X,
                                               const float* __restrict__ W,
                                               const float* __restrict__ bias,
                                               float* __restrict__ C) {
    __shared__ float As[16][132];   // [k][m]
    __shared__ float Bs[16][132];   // [k][n]

    const int tid = threadIdx.x;
    const int tx = tid & 15;
    const int ty = tid >> 4;
    const int m0 = blockIdx.y * 128;
    const int n0 = blockIdx.x * 128;

    float acc[8][8] = {};
    float4 ra[2], rb[2];

    // prefetch tile k0=0
    #pragma unroll
    for (int i = 0; i < 2; ++i) {
        int f4 = tid + i * 256;
        ra[i] = *(const float4*)(X + (size_t)(m0 + (f4 >> 2)) * DD + (f4 & 3) * 4);
        rb[i] = *(const float4*)(W + (size_t)(f4 >> 5) * G4 + n0 + (f4 & 31) * 4);
    }

    for (int k0 = 0; k0 < DD; k0 += 16) {
        // stage current tile registers -> LDS
        #pragma unroll
        for (int i = 0; i < 2; ++i) {
            int f4 = tid + i * 256;
            int mi = f4 >> 2, kq = f4 & 3;
            As[kq * 4 + 0][mi] = ra[i].x;
            As[kq * 4 + 1][mi] = ra[i].y;
            As[kq * 4 + 2][mi] = ra[i].z;
            As[kq * 4 + 3][mi] = ra[i].w;
            *(float4*)&Bs[f4 >> 5][(f4 & 31) * 4] = rb[i];
        }
        __syncthreads();

        // issue next tile's loads (redundant re-load of last tile at the end —
        // always a valid address, keeps the loop branch-free)
        const int kn = (k0 + 16 < DD) ? (k0 + 16) : k0;
        #pragma unroll
        for (int i = 0; i < 2; ++i) {
            int f4 = tid + i * 256;
            ra[i] = *(const float4*)(X + (size_t)(m0 + (f4 >> 2)) * DD + kn + (f4 & 3) * 4);
            rb[i] = *(const float4*)(W + (size_t)(kn + (f4 >> 5)) * G4 + n0 + (f4 & 31) * 4);
        }

        #pragma unroll
        for (int kk = 0; kk < 16; ++kk) {
            float ar[8], br[8];
            *(float4*)&ar[0] = *(const float4*)&As[kk][ty * 4];
            *(float4*)&ar[4] = *(const float4*)&As[kk][64 + ty * 4];
            *(float4*)&br[0] = *(const float4*)&Bs[kk][tx * 4];
            *(float4*)&br[4] = *(const float4*)&Bs[kk][64 + tx * 4];
            #pragma unroll
            for (int i = 0; i < 8; ++i)
                #pragma unroll
                for (int j = 0; j < 8; ++j)
                    acc[i][j] += ar[i] * br[j];
        }
        __syncthreads();
    }

    float bl[8];
    *(float4*)&bl[0] = *(const float4*)(bias + n0 + tx * 4);
    *(float4*)&bl[4] = *(const float4*)(bias + n0 + 64 + tx * 4);
    #pragma unroll
    for (int i = 0; i < 8; ++i) {
        int mrow = m0 + ty * 4 + (i & 3) + 64 * (i >> 2);
        float* crow = C + (size_t)mrow * G4 + n0;
        float4 o1, o2;
        o1.x = acc[i][0] + bl[0]; o1.y = acc[i][1] + bl[1];
        o1.z = acc[i][2] + bl[2]; o1.w = acc[i][3] + bl[3];
        o2.x = acc[i][4] + bl[4]; o2.y = acc[i][5] + bl[5];
        o2.z = acc[i][6] + bl[6]; o2.w = acc[i][7] + bl[7];
        *(float4*)(crow + tx * 4) = o1;
        *(float4*)(crow + 64 + tx * 4) = o2;
    }
}

// ---------------------------------------------------------------------------
// Split-K recurrent matmul: partial[kc][b][g] = sum_{k in chunk} h[b][k]*Wh[k][g]
// Grid: KS*16 wgs (gtile = bx&15 covers 256 g-cols, kc = bx>>4). 256 threads:
// gthr = tid&31 (8 g-cols as 2 float4 strided 128), bthr = tid>>5 (8 b-rows).
// 8x8 register tile: 64 B loaded per 128 FLOP; weight loads coalesced 512 B
// per 32-lane group; h from LDS (2 broadcast b128 reads / k).
template <int KS>
__global__ __launch_bounds__(256) void lstm_mm(const float* __restrict__ hprev,
                                               const float* __restrict__ Wh,
                                               float* __restrict__ partial) {
    constexpr int CH = HH / KS;      // k-chunk length (32 or 64)
    constexpr int C4 = CH / 4;
    __shared__ float hs[CH][68];     // [k][b], stride 68 (16B-aligned, padded)

    const int tid = threadIdx.x;
    const int gthr = tid & 31;
    const int bthr = tid >> 5;
    const int gtile = blockIdx.x & 15;
    const int kc = blockIdx.x >> 4;
    const int g0 = gtile * 256;
    const int k0 = kc * CH;

    // stage h[0:64][k0:k0+CH] transposed into LDS
    #pragma unroll
    for (int i = 0; i < C4 / 4; ++i) {
        int f4 = tid + 256 * i;          // 0 .. 64*C4-1
        int b = f4 / C4;
        int q = f4 % C4;
        float4 v = *(const float4*)(hprev + (size_t)b * HH + k0 + q * 4);
        hs[q * 4 + 0][b] = v.x;
        hs[q * 4 + 1][b] = v.y;
        hs[q * 4 + 2][b] = v.z;
        hs[q * 4 + 3][b] = v.w;
    }
    __syncthreads();

    float acc[8][8] = {};
    const float* wp = Wh + (size_t)k0 * G4 + g0 + (gthr << 2);

    #pragma unroll 4
    for (int k = 0; k < CH; ++k) {
        float4 w0 = *(const float4*)wp;
        float4 w1 = *(const float4*)(wp + 128);
        wp += G4;
        float hv[8];
        *(float4*)&hv[0] = *(const float4*)&hs[k][bthr * 8];
        *(float4*)&hv[4] = *(const float4*)&hs[k][bthr * 8 + 4];
        #pragma unroll
        for (int i = 0; i < 8; ++i) {
            acc[i][0] += hv[i] * w0.x;
            acc[i][1] += hv[i] * w0.y;
            acc[i][2] += hv[i] * w0.z;
            acc[i][3] += hv[i] * w0.w;
            acc[i][4] += hv[i] * w1.x;
            acc[i][5] += hv[i] * w1.y;
            acc[i][6] += hv[i] * w1.z;
            acc[i][7] += hv[i] * w1.w;
        }
    }

    #pragma unroll
    for (int i = 0; i < 8; ++i) {
        int b = bthr * 8 + i;
        float* pp = partial + ((size_t)(kc * BB + b)) * G4 + g0 + (gthr << 2);
        float4 o1, o2;
        o1.x = acc[i][0]; o1.y = acc[i][1]; o1.z = acc[i][2]; o1.w = acc[i][3];
        o2.x = acc[i][4]; o2.y = acc[i][5]; o2.z = acc[i][6]; o2.w = acc[i][7];
        *(float4*)pp = o1;
        *(float4*)(pp + 128) = o2;
    }
}

// ---------------------------------------------------------------------------
// Reduce partials + Gx[t], apply hard-LSTM cell, write c and h(=out[t]).
// nkc==0 => t==0 (no recurrent term, c_prev = 0).
__global__ __launch_bounds__(256) void cell_kernel(const float* __restrict__ Gxt,
                                                   const float* __restrict__ partial,
                                                   float* __restrict__ cbuf,
                                                   float* __restrict__ hout,
                                                   int nkc) {
    const int idx = blockIdx.x * 256 + threadIdx.x;  // 0..65535
    const int b = idx >> 10;
    const int hc = idx & 1023;

    const float* gr = Gxt + (size_t)b * G4 + hc;
    float gi = gr[0];
    float gf = gr[HH];
    float gg = gr[2 * HH];
    float go = gr[3 * HH];

    #pragma unroll 8
    for (int kc = 0; kc < nkc; ++kc) {
        const float* p = partial + ((size_t)(kc * BB + b)) * G4 + hc;
        gi += p[0];
        gf += p[HH];
        gg += p[2 * HH];
        go += p[3 * HH];
    }

    float ii = hsig(gi);
    float ff = hsig(gf);
    float gv = htanh(gg);
    float oo = hsig(go);

    float cv = (nkc > 0) ? cbuf[idx] : 0.0f;
    float cn = ff * cv + ii * gv;
    cbuf[idx] = cn;
    float hn = oo * htanh(cn);
    hout[idx] = hn;
}

// ---------------------------------------------------------------------------
extern "C" void kernel_launch(void* const* d_in, const int* in_sizes, int n_in,
                              void* d_out, int out_size, void* d_ws, size_t ws_size,
                              hipStream_t stream) {
    const float* x  = (const float*)d_in[0];   // [T,B,D]
    const float* Wx = (const float*)d_in[1];   // [D,4H]
    const float* Wh = (const float*)d_in[2];   // [H,4H]
    const float* bs = (const float*)d_in[3];   // [4H]
    float* out = (float*)d_out;                // [T,B,H] — doubles as h history

    // ws layout (floats): Gx (128 MiB) | partial (KS MiB) | cbuf (0.25 MiB)
    float* Gx = (float*)d_ws;
    const size_t gx_elems = (size_t)MM * G4;            // 33,554,432
    const size_t need32 = (gx_elems + (size_t)32 * BB * G4 + BH) * 4;
    const bool ks32 = (ws_size >= need32);               // deterministic per run
    const int KS = ks32 ? 32 : 16;                       // KS=16 proven to fit
    float* partial = Gx + gx_elems;
    float* cbuf = partial + (size_t)KS * BB * G4;

    // Gx = X @ Wx + b for all timesteps at once
    gx_gemm<<<dim3(G4 / 128, MM / 128), dim3(256), 0, stream>>>(x, Wx, bs, Gx);

    // t = 0: gates = Gx[0] only (h0 = c0 = 0)
    cell_kernel<<<dim3(BH / 256), dim3(256), 0, stream>>>(
        Gx, partial, cbuf, out, 0);

    // t = 1..127
    for (int t = 1; t < TT; ++t) {
        const float* hprev = out + (size_t)(t - 1) * BH;
        if (ks32)
            lstm_mm<32><<<dim3(32 * 16), dim3(256), 0, stream>>>(hprev, Wh, partial);
        else
            lstm_mm<16><<<dim3(16 * 16), dim3(256), 0, stream>>>(hprev, Wh, partial);
        cell_kernel<<<dim3(BH / 256), dim3(256), 0, stream>>>(
            Gx + (size_t)t * BB * G4, partial, cbuf, out + (size_t)t * BH, KS);
    }
}